// Round 1
// baseline (327.561 us; speedup 1.0000x reference)
//
#include <hip/hip_runtime.h>
#include <math.h>

#define BLOCK 256
#define PPT 4                  // rows per thread -> 1024 rows per block
#define RPB (BLOCK * PPT)      // 1024
#define CLEN 32                // cols per reduce round (scmin width)
#define CTILES 8               // col sub-tiles per block -> 256 cols per block
#define CPB (CLEN * CTILES)    // 256
#define SPAD 257               // scmin padded stride (bank = (c+i)%32, conflict-free)
#define FBLOCKS 128

typedef float f32x2 __attribute__((ext_vector_type(2)));

// ---- order-preserving float <-> uint key (works for negatives) ----
__device__ __forceinline__ unsigned f2key(float f) {
    unsigned b = __float_as_uint(f);
    return b ^ ((b & 0x80000000u) ? 0xFFFFFFFFu : 0x80000000u);
}
__device__ __forceinline__ float key2f(unsigned k) {
    unsigned b = k ^ ((k & 0x80000000u) ? 0x80000000u : 0xFFFFFFFFu);
    return __uint_as_float(b);
}
__device__ __forceinline__ float min3f(float a, float b, float c) {
    return fminf(fminf(a, b), c);   // -> v_min3_f32
}

// Block = 1024 rows x 256 cols (8 sub-tiles of 32 cols) for one batch.
// d = a^2 + b^2 - 2ab computed ONCE per pair, as packed-f32 (2 cols per
// f32x2 lane-pair -> v_pk_fma_f32 on gfx950):
//   - row mins (dist1): register accumulators persist across ALL 256 cols
//     -> 1 atomicMin per row per block (was 8x more with 32-col blocks)
//   - col mins (dist2): per-thread fold over its 4 rows -> scmin[col][tid],
//     block tree-reduce per 32-col sub-tile, one atomicMin per col.
// Cross-block combine via global atomicMin on order-keys (memset 0xFF first).
__global__ __launch_bounds__(BLOCK, 4) void chamfer_tile_kernel(
    const float* __restrict__ arr1, const float* __restrict__ arr2,
    int N, int M,
    unsigned* __restrict__ rkey, unsigned* __restrict__ ckey,
    float* __restrict__ out)
{
    const int b  = blockIdx.z;
    const int r0 = blockIdx.x * RPB;     // row offset within batch
    const int c0 = blockIdx.y * CPB;     // col offset within batch

    // Zero the output accumulator exactly once (finalize is a later dispatch).
    if (blockIdx.x == 0 && blockIdx.y == 0 && b == 0 && threadIdx.x == 0)
        out[0] = 0.0f;

    // SoA col staging so packed loads are natural ds_read_b64 pairs.
    __shared__ __align__(16) float sbx[CPB], sby[CPB], sbz[CPB], sbw[CPB];
    __shared__ float scmin[CLEN][SPAD];
    __shared__ float cred[8][CLEN];

    // Stage all 256 col points, prescaled: (-2x, -2y, -2z) and |b|^2.
    {
        const float* p = arr2 + ((size_t)b * M + c0 + threadIdx.x) * 3;
        float x = p[0], y = p[1], z = p[2];
        sbx[threadIdx.x] = -2.0f * x;
        sby[threadIdx.x] = -2.0f * y;
        sbz[threadIdx.x] = -2.0f * z;
        sbw[threadIdx.x] = __builtin_fmaf(x, x, __builtin_fmaf(y, y, z * z));
    }

    // Row points in registers (+ their squared norms)
    float ax[PPT], ay[PPT], az[PPT], a2[PPT], mn[PPT];
    const float* abase = arr1 + ((size_t)b * N + r0) * 3;
#pragma unroll
    for (int k = 0; k < PPT; ++k) {
        int idx = threadIdx.x + k * BLOCK;
        float x = abase[idx * 3 + 0];
        float y = abase[idx * 3 + 1];
        float z = abase[idx * 3 + 2];
        ax[k] = x; ay[k] = y; az[k] = z;
        a2[k] = __builtin_fmaf(x, x, __builtin_fmaf(y, y, z * z));
        mn[k] = __builtin_inff();
    }
    __syncthreads();

#pragma unroll 1
    for (int s = 0; s < CTILES; ++s) {
        const int cb = s * CLEN;

        // Inner scan: 2 cols per f32x2, jj fully unrolled (16 iters).
        // Per (2-col, k): 1 pk_add + 3 pk_fma + 1 min3(row) + col fold.
#pragma unroll
        for (int jj = 0; jj < CLEN; jj += 2) {
            f32x2 bx = *(const f32x2*)&sbx[cb + jj];
            f32x2 by = *(const f32x2*)&sby[cb + jj];
            f32x2 bz = *(const f32x2*)&sbz[cb + jj];
            f32x2 bw = *(const f32x2*)&sbw[cb + jj];
            f32x2 cm;
            {   // k = 0 seeds the col fold
                f32x2 t = bw + (f32x2){a2[0], a2[0]};
                f32x2 d = __builtin_elementwise_fma(bx, (f32x2){ax[0], ax[0]},
                          __builtin_elementwise_fma(by, (f32x2){ay[0], ay[0]},
                          __builtin_elementwise_fma(bz, (f32x2){az[0], az[0]}, t)));
                mn[0] = min3f(mn[0], d.x, d.y);   // row min
                cm = d;
            }
#pragma unroll
            for (int k = 1; k < PPT; ++k) {
                f32x2 t = bw + (f32x2){a2[k], a2[k]};
                f32x2 d = __builtin_elementwise_fma(bx, (f32x2){ax[k], ax[k]},
                          __builtin_elementwise_fma(by, (f32x2){ay[k], ay[k]},
                          __builtin_elementwise_fma(bz, (f32x2){az[k], az[k]}, t)));
                mn[k] = min3f(mn[k], d.x, d.y);   // row min
                cm = __builtin_elementwise_min(cm, d);
            }
            scmin[jj][threadIdx.x]     = cm.x;  // bank (jj+tid)%32: 2-way, free
            scmin[jj + 1][threadIdx.x] = cm.y;
        }
        __syncthreads();

        // Col reduce stage 1: thread (c = tid&31, seg = tid>>5) tree-reduces
        // scmin[c][seg*32 .. seg*32+31].  bank = (c+i)%32 -> <=2-way (free).
        {
            int c = threadIdx.x & 31, seg = threadIdx.x >> 5;
            const float* row = &scmin[c][seg * 32];
            float v0 = row[0], v1 = row[1];
#pragma unroll
            for (int i = 2; i < 32; i += 2) {
                v0 = fminf(v0, row[i]);
                v1 = fminf(v1, row[i + 1]);
            }
            cred[seg][c] = fminf(v0, v1);
        }
        __syncthreads();

        // Stage 2: 32 threads fold the 8 segment partials, one atomic per col.
        // (Safe vs next round: its scmin writes start only after the NEXT
        //  __syncthreads, which these threads must also reach.)
        if (threadIdx.x < CLEN) {
            float v = fminf(min3f(min3f(min3f(cred[0][threadIdx.x],
                                              cred[1][threadIdx.x],
                                              cred[2][threadIdx.x]),
                                        cred[3][threadIdx.x],
                                        cred[4][threadIdx.x]),
                                  cred[5][threadIdx.x],
                                  cred[6][threadIdx.x]),
                            cred[7][threadIdx.x]);
            atomicMin(&ckey[(size_t)b * M + c0 + cb + threadIdx.x], f2key(v));
        }
    }

    // Row partials -> global atomic min (ONE per row per block, covers 256 cols)
    unsigned* rk = rkey + (size_t)b * N + r0;
#pragma unroll
    for (int k = 0; k < PPT; ++k)
        atomicMin(&rk[threadIdx.x + k * BLOCK], f2key(mn[k]));
}

// Finalize: keys already hold full d mins (a^2 and b^2 included) -> just a
// weighted sum of 64k values (0.26 MB), one atomicAdd per block.
__global__ __launch_bounds__(256) void chamfer_finalize_kernel(
    const unsigned* __restrict__ rkey, const unsigned* __restrict__ ckey,
    int BN, int BM, float* __restrict__ out)
{
    const float wA = 1.0f / (float)BN;
    const float wB = 1.0f / (float)BM;
    const int stride = 256 * FBLOCKS;

    float s = 0.0f;
    for (int i = blockIdx.x * 256 + threadIdx.x; i < BN; i += stride)
        s += wA * key2f(rkey[i]);
    for (int i = blockIdx.x * 256 + threadIdx.x; i < BM; i += stride)
        s += wB * key2f(ckey[i]);

#pragma unroll
    for (int off = 32; off > 0; off >>= 1)
        s += __shfl_down(s, off, 64);

    __shared__ float wsum[4];
    int lane = threadIdx.x & 63, wv = threadIdx.x >> 6;
    if (lane == 0) wsum[wv] = s;
    __syncthreads();
    if (threadIdx.x == 0)
        atomicAdd(out, wsum[0] + wsum[1] + wsum[2] + wsum[3]);
}

extern "C" void kernel_launch(void* const* d_in, const int* in_sizes, int n_in,
                              void* d_out, int out_size, void* d_ws, size_t ws_size,
                              hipStream_t stream)
{
    const float* arr1 = (const float*)d_in[0];
    const float* arr2 = (const float*)d_in[1];
    float* out = (float*)d_out;

    const int Bb = 4;
    const int N = in_sizes[0] / (Bb * 3);   // 8192
    const int M = in_sizes[1] / (Bb * 3);   // 8192
    const int BN = Bb * N, BM = Bb * M;

    unsigned* rkey = (unsigned*)d_ws;        // [BN]
    unsigned* ckey = rkey + BN;              // [BM]

    // Init all min-keys to 0xFFFFFFFF (max) — ws is poisoned 0xAA each launch.
    hipMemsetAsync(rkey, 0xFF, (size_t)(BN + BM) * sizeof(unsigned), stream);

    dim3 grid(N / RPB, M / CPB, Bb);        // (8, 32, 4) = 1024 blocks, 4/CU
    chamfer_tile_kernel<<<grid, BLOCK, 0, stream>>>(arr1, arr2, N, M,
                                                    rkey, ckey, out);

    chamfer_finalize_kernel<<<FBLOCKS, 256, 0, stream>>>(rkey, ckey, BN, BM, out);
}

// Round 2
// 87.366 us; speedup vs baseline: 3.7493x; 3.7493x over previous
//
#include <hip/hip_runtime.h>
#include <math.h>

#define BLOCK 256
#define PPT 8               // rows per thread -> 2048 rows per block
#define RPB (BLOCK * PPT)   // 2048
#define CLEN 32             // cols per block tile
#define SPAD 257            // scmin padded stride (bank = (c+i)%32, conflict-free)
#define FBLOCKS 128

typedef float f32x2 __attribute__((ext_vector_type(2)));

// ---- order-preserving float <-> uint key (works for negatives) ----
__device__ __forceinline__ unsigned f2key(float f) {
    unsigned b = __float_as_uint(f);
    return b ^ ((b & 0x80000000u) ? 0xFFFFFFFFu : 0x80000000u);
}
__device__ __forceinline__ float key2f(unsigned k) {
    unsigned b = k ^ ((k & 0x80000000u) ? 0x80000000u : 0xFFFFFFFFu);
    return __uint_as_float(b);
}
__device__ __forceinline__ float min3f(float a, float b, float c) {
    return fminf(fminf(a, b), c);   // -> v_min3_f32
}
__device__ __forceinline__ f32x2 pkfma(f32x2 a, f32x2 b, f32x2 c) {
    return __builtin_elementwise_fma(a, b, c);   // -> v_pk_fma_f32
}

// ROUND-0 STRUCTURE (proven <=39.6us), single change: packed-f32 inner loop.
// Block = (2048 rows of array1) x (32 cols of array2) for one batch.
// Col points staged SoA (sbx/sby/sbz/sbw) so {col j, col j+1} components sit
// in consecutive VGPRs -> v_pk_fma_f32/v_pk_add_f32 handle 2 cols per slot:
// per (2 cols, 2 rows): 2 pk_add + 6 pk_fma + 2 min3(row) + 2 min3(col)
// = 12 slots / 4 pairs = 3.0 slots/pair (was 5.5 scalar).
//   - row mins (dist1): register accumulators
//   - col mins (dist2): per-thread min3-fold over 8 rows -> scmin[col][tid],
//     block tree-reduce, one atomicMin per col
// Cross-block combine via global atomicMin on order-keys (memset 0xFF first).
__global__ __launch_bounds__(BLOCK, 4) void chamfer_tile_kernel(
    const float* __restrict__ arr1, const float* __restrict__ arr2,
    int N, int M,
    unsigned* __restrict__ rkey, unsigned* __restrict__ ckey,
    float* __restrict__ out)
{
    const int b  = blockIdx.z;
    const int r0 = blockIdx.x * RPB;     // row offset within batch
    const int c0 = blockIdx.y * CLEN;    // col offset within batch

    // Zero the output accumulator exactly once (finalize is a later dispatch).
    if (blockIdx.x == 0 && blockIdx.y == 0 && b == 0 && threadIdx.x == 0)
        out[0] = 0.0f;

    // SoA col staging: packed pairs load as single ds_read_b64 (uniform addr).
    __shared__ __align__(16) float sbx[CLEN], sby[CLEN], sbz[CLEN], sbw[CLEN];
    __shared__ float scmin[CLEN][SPAD];
    __shared__ float cred[8][CLEN];

    // Stage col points, prescaled: (-2x, -2y, -2z) and |b|^2.
    if (threadIdx.x < CLEN) {
        const float* p = arr2 + ((size_t)b * M + c0 + threadIdx.x) * 3;
        float x = p[0], y = p[1], z = p[2];
        sbx[threadIdx.x] = -2.0f * x;
        sby[threadIdx.x] = -2.0f * y;
        sbz[threadIdx.x] = -2.0f * z;
        sbw[threadIdx.x] = __builtin_fmaf(x, x, __builtin_fmaf(y, y, z * z));
    }
    __syncthreads();

    // Row points in registers (+ their squared norms)
    float ax[PPT], ay[PPT], az[PPT], a2[PPT], mn[PPT];
    const float* abase = arr1 + ((size_t)b * N + r0) * 3;
#pragma unroll
    for (int k = 0; k < PPT; ++k) {
        int idx = threadIdx.x + k * BLOCK;
        float x = abase[idx * 3 + 0];
        float y = abase[idx * 3 + 1];
        float z = abase[idx * 3 + 2];
        ax[k] = x; ay[k] = y; az[k] = z;
        a2[k] = __builtin_fmaf(x, x, __builtin_fmaf(y, y, z * z));
        mn[k] = __builtin_inff();
    }

    // Inner scan: 2 cols per f32x2, rows in pairs, fully unrolled.
#pragma unroll
    for (int jj = 0; jj < CLEN; jj += 2) {
        f32x2 bx = *(const f32x2*)&sbx[jj];
        f32x2 by = *(const f32x2*)&sby[jj];
        f32x2 bz = *(const f32x2*)&sbz[jj];
        f32x2 bw = *(const f32x2*)&sbw[jj];
        float cx, cy;                      // col-fold accumulators (2 cols)
#pragma unroll
        for (int k = 0; k < PPT; k += 2) {
            f32x2 t0 = bw + (f32x2){a2[k],     a2[k]};
            f32x2 t1 = bw + (f32x2){a2[k + 1], a2[k + 1]};
            f32x2 d0 = pkfma(bx, (f32x2){ax[k], ax[k]},
                       pkfma(by, (f32x2){ay[k], ay[k]},
                       pkfma(bz, (f32x2){az[k], az[k]}, t0)));
            f32x2 d1 = pkfma(bx, (f32x2){ax[k + 1], ax[k + 1]},
                       pkfma(by, (f32x2){ay[k + 1], ay[k + 1]},
                       pkfma(bz, (f32x2){az[k + 1], az[k + 1]}, t1)));
            mn[k]     = min3f(mn[k],     d0.x, d0.y);   // row mins
            mn[k + 1] = min3f(mn[k + 1], d1.x, d1.y);
            if (k == 0) {                               // col fold seed
                cx = fminf(d0.x, d1.x);
                cy = fminf(d0.y, d1.y);
            } else {                                    // col fold: min3
                cx = min3f(cx, d0.x, d1.x);
                cy = min3f(cy, d0.y, d1.y);
            }
        }
        scmin[jj][threadIdx.x]     = cx;   // bank (jj+tid)%32: 2-way max, free
        scmin[jj + 1][threadIdx.x] = cy;
    }

    // Row partials -> global atomic min
    unsigned* rk = rkey + (size_t)b * N + r0;
#pragma unroll
    for (int k = 0; k < PPT; ++k)
        atomicMin(&rk[threadIdx.x + k * BLOCK], f2key(mn[k]));

    __syncthreads();

    // Col reduce stage 1: thread (c = tid&31, s = tid>>5) tree-reduces
    // scmin[c][s*32 .. s*32+31].  bank = (c+i)%32 -> <=2-way (free).
    {
        int c = threadIdx.x & 31, s = threadIdx.x >> 5;
        const float* row = &scmin[c][s * 32];
        float v0 = row[0], v1 = row[1];
#pragma unroll
        for (int i = 2; i < 32; i += 2) {
            v0 = fminf(v0, row[i]);
            v1 = fminf(v1, row[i + 1]);
        }
        cred[s][c] = fminf(v0, v1);
    }
    __syncthreads();
    // Stage 2: 32 threads fold the 8 segment partials, one atomic per col.
    if (threadIdx.x < CLEN) {
        float v = fminf(min3f(min3f(min3f(cred[0][threadIdx.x],
                                          cred[1][threadIdx.x],
                                          cred[2][threadIdx.x]),
                                    cred[3][threadIdx.x],
                                    cred[4][threadIdx.x]),
                              cred[5][threadIdx.x],
                              cred[6][threadIdx.x]),
                        cred[7][threadIdx.x]);
        atomicMin(&ckey[(size_t)b * M + c0 + threadIdx.x], f2key(v));
    }
}

// Finalize: keys already hold full d mins (a^2 and b^2 included) -> just a
// weighted sum of 64k values (0.26 MB), one atomicAdd per block.
__global__ __launch_bounds__(256) void chamfer_finalize_kernel(
    const unsigned* __restrict__ rkey, const unsigned* __restrict__ ckey,
    int BN, int BM, float* __restrict__ out)
{
    const float wA = 1.0f / (float)BN;
    const float wB = 1.0f / (float)BM;
    const int stride = 256 * FBLOCKS;

    float s = 0.0f;
    for (int i = blockIdx.x * 256 + threadIdx.x; i < BN; i += stride)
        s += wA * key2f(rkey[i]);
    for (int i = blockIdx.x * 256 + threadIdx.x; i < BM; i += stride)
        s += wB * key2f(ckey[i]);

#pragma unroll
    for (int off = 32; off > 0; off >>= 1)
        s += __shfl_down(s, off, 64);

    __shared__ float wsum[4];
    int lane = threadIdx.x & 63, wv = threadIdx.x >> 6;
    if (lane == 0) wsum[wv] = s;
    __syncthreads();
    if (threadIdx.x == 0)
        atomicAdd(out, wsum[0] + wsum[1] + wsum[2] + wsum[3]);
}

extern "C" void kernel_launch(void* const* d_in, const int* in_sizes, int n_in,
                              void* d_out, int out_size, void* d_ws, size_t ws_size,
                              hipStream_t stream)
{
    const float* arr1 = (const float*)d_in[0];
    const float* arr2 = (const float*)d_in[1];
    float* out = (float*)d_out;

    const int Bb = 4;
    const int N = in_sizes[0] / (Bb * 3);   // 8192
    const int M = in_sizes[1] / (Bb * 3);   // 8192
    const int BN = Bb * N, BM = Bb * M;

    unsigned* rkey = (unsigned*)d_ws;        // [BN]
    unsigned* ckey = rkey + BN;              // [BM]

    // Init all min-keys to 0xFFFFFFFF (max) — ws is poisoned 0xAA each launch.
    hipMemsetAsync(rkey, 0xFF, (size_t)(BN + BM) * sizeof(unsigned), stream);

    dim3 grid(N / RPB, M / CLEN, Bb);       // (4, 256, 4) = 4096 blocks
    chamfer_tile_kernel<<<grid, BLOCK, 0, stream>>>(arr1, arr2, N, M,
                                                    rkey, ckey, out);

    chamfer_finalize_kernel<<<FBLOCKS, 256, 0, stream>>>(rkey, ckey, BN, BM, out);
}